// Round 1
// baseline (114.672 us; speedup 1.0000x reference)
//
#include <hip/hip_runtime.h>

typedef __bf16 bf16x8_t __attribute__((ext_vector_type(8)));
typedef float  f32x4_t  __attribute__((ext_vector_type(4)));

#define EDGES 28
#define TIN   4096
#define T2V   8192
#define NB    16
#define CIN   224
#define COUT  448

__device__ __forceinline__ unsigned short f2bf(float f) {
    unsigned int u = __builtin_bit_cast(unsigned int, f);
    u = (u + 0x7fffu + ((u >> 16) & 1u)) >> 16;   // RNE
    return (unsigned short)u;
}
__device__ __forceinline__ float bf2f(unsigned short h) {
    unsigned int u = ((unsigned int)h) << 16;
    return __builtin_bit_cast(float, u);
}

// ---------------------------------------------------------------------------
// Prep: fold (mask ∘ region-unpool ∘ upsample) into per-parity MFMA A-frags.
// A[eo][s][d]: 16(co) x 32(j = slot*16+ci) bf16, stored frag-ready:
//   lane l holds A[row=l&15][k=(l>>4)*8+e], e=0..7  (16B per lane)
// Also emits fp32 correction weights Wc0 (y[-1] pad) and Wc2 (y[2T] pad).
// ---------------------------------------------------------------------------
__global__ void prep_fold(const float* __restrict__ w,
                          unsigned short* __restrict__ abf,
                          float* __restrict__ wc0,
                          float* __restrict__ wc2) {
    int tid = blockIdx.x * 256 + threadIdx.x;
    if (tid >= EDGES * 2 * 3 * 64) return;
    int l = tid & 63;
    int r = tid >> 6;
    int d = r % 3; r /= 3;
    int s = r & 1;
    int eo = r >> 1;
    int co = l & 15;
    int r0 = (eo == 0) ? 0 : ((eo - 1) >> 1);
    int r1 = (eo == EDGES - 1) ? ((EDGES - 1) >> 1) : ((eo + 1) >> 1);
    int elo = (eo == 0) ? 0 : eo - 1;
    int ehi = (eo == EDGES - 1) ? EDGES - 1 : eo + 1;
    unsigned short out8[8];
    for (int e = 0; e < 8; ++e) {
        int j = (l >> 4) * 8 + e;       // 0..31
        int slot = j >> 4, ci = j & 15;
        float W0 = 0.f, W1 = 0.f, W2 = 0.f;
        for (int ei = elo; ei <= ehi; ++ei) {           // ei in ADJ(eo)
            int re = ei >> 1;
            bool take = slot ? (r1 != r0 && re == r1) : (re == r0);
            if (!take) continue;
            const float* wp = w + ((size_t)(eo * 16 + co) * COUT + (ei * 16 + ci)) * 3;
            W0 += wp[0]; W1 += wp[1]; W2 += wp[2];
        }
        // fold upsample (align_corners=False): y[2m]=.25x[m-1]+.75x[m]; y[2m+1]=.75x[m]+.25x[m+1]
        float a;
        if (s == 0) {   // even t2 = 2m: taps on x[m-1], x[m], x[m+1]
            a = (d == 0) ? 0.75f * W0 + 0.25f * W1
              : (d == 1) ? 0.25f * W0 + 0.75f * W1 + 0.75f * W2
                         : 0.25f * W2;
        } else {        // odd t2 = 2m+1
            a = (d == 0) ? 0.25f * W0
              : (d == 1) ? 0.75f * W0 + 0.75f * W1 + 0.25f * W2
                         : 0.25f * W1 + 0.75f * W2;
        }
        out8[e] = f2bf(a);
        if (s == 0 && d == 0) {
            wc0[(eo * 16 + co) * 32 + j] = W0;
            wc2[(eo * 16 + co) * 32 + j] = W2;
        }
    }
    #pragma unroll
    for (int e = 0; e < 8; ++e) abf[(size_t)tid * 8 + e] = out8[e];
}

// ---------------------------------------------------------------------------
// Main: one block = (eo, b, 256 m-positions = 512 t2). 4 waves x 4 m-tiles.
// LDS: x as bf16, transposed [mr=0..257][32 ch], 64B rows, XOR-swizzled.
// ---------------------------------------------------------------------------
__global__ __launch_bounds__(256)
void skel_main(const float* __restrict__ x,
               const float* __restrict__ bias,
               const unsigned short* __restrict__ abf,
               const float* __restrict__ wc0,
               const float* __restrict__ wc2,
               float* __restrict__ out) {
    __shared__ __align__(16) unsigned short lds[258 * 32];
    const int tb = blockIdx.x;          // m-tile block 0..15
    const int eo = blockIdx.y;          // 0..27
    const int b  = blockIdx.z;          // 0..15
    const int t  = threadIdx.x;
    const int mstart = tb << 8;
    const int r0 = (eo == 0) ? 0 : ((eo - 1) >> 1);
    const int r1 = (eo == EDGES - 1) ? ((EDGES - 1) >> 1) : ((eo + 1) >> 1);

    // ---- stage x -> LDS (bf16, [m][ch] transposed, swizzled) ----
    {
        int j = t >> 3;                                     // ch 0..31
        int gch = (j < 16) ? (r0 * 16 + j) : (r1 * 16 + (j - 16));
        const float* xrow = x + ((size_t)b * CIN + gch) * TIN;
        int ccol = (j >> 3) * 16 + (j & 7) * 2;             // byte col in row
        #pragma unroll
        for (int it = 0; it < 8; ++it) {
            int c = (t & 7) + it * 8;                       // 0..63 float4s
            float4 v = *(const float4*)(xrow + mstart + c * 4);
            unsigned short bb[4] = { f2bf(v.x), f2bf(v.y), f2bf(v.z), f2bf(v.w) };
            #pragma unroll
            for (int q = 0; q < 4; ++q) {
                int mr = 1 + c * 4 + q;                     // rows 1..256
                int byte = (mr << 6) + ccol;
                byte ^= ((mr >> 1) & 7) << 4;               // bank swizzle
                *(unsigned short*)((char*)lds + byte) = bb[q];
            }
        }
    }
    if (t < 64) {   // edge columns mr=0 (m=mstart-1) and mr=257 (m=mstart+256), clamped
        int j = t & 31;
        int gch = (j < 16) ? (r0 * 16 + j) : (r1 * 16 + (j - 16));
        int mr, m;
        if (t < 32) { mr = 0;   m = mstart - 1;   if (m < 0) m = 0; }
        else        { mr = 257; m = mstart + 256; if (m > TIN - 1) m = TIN - 1; }
        float v = x[((size_t)b * CIN + gch) * TIN + m];
        int byte = (mr << 6) + (j >> 3) * 16 + (j & 7) * 2;
        byte ^= ((mr >> 1) & 7) << 4;
        *(unsigned short*)((char*)lds + byte) = f2bf(v);
    }

    const int l  = t & 63;
    const int wv = t >> 6;

    // A-frags (held in VGPRs for whole kernel): [parity][d]
    bf16x8_t afr[2][3];
    #pragma unroll
    for (int s = 0; s < 2; ++s)
        #pragma unroll
        for (int d = 0; d < 3; ++d) {
            int4 tmp = *(const int4*)(abf + (size_t)(((eo * 2 + s) * 3 + d) * 64 + l) * 8);
            afr[s][d] = __builtin_bit_cast(bf16x8_t, tmp);
        }
    float bco[4];
    #pragma unroll
    for (int rr = 0; rr < 4; ++rr) bco[rr] = bias[eo * 16 + (l >> 4) * 4 + rr];

    __syncthreads();

    const int lc = l & 15;   // D col / B col -> m offset
    const int lg = l >> 4;
    float* obase = out + ((size_t)b * COUT + eo * 16) * (size_t)T2V;

    #pragma unroll
    for (int tile = 0; tile < 4; ++tile) {
        int mloc = wv * 64 + tile * 16;
        f32x4_t acc0 = {0.f, 0.f, 0.f, 0.f};   // even t2
        f32x4_t acc1 = {0.f, 0.f, 0.f, 0.f};   // odd t2
        #pragma unroll
        for (int d = 0; d < 3; ++d) {
            int lmr = mloc + lc + d;                 // LDS row (m + d - 1 + 1)
            int byte = (lmr << 6) + lg * 16;
            byte ^= ((lmr >> 1) & 7) << 4;
            int4 bd = *(const int4*)((char*)lds + byte);
            bf16x8_t bfr = __builtin_bit_cast(bf16x8_t, bd);
            acc0 = __builtin_amdgcn_mfma_f32_16x16x32_bf16(afr[0][d], bfr, acc0, 0, 0, 0);
            acc1 = __builtin_amdgcn_mfma_f32_16x16x32_bf16(afr[1][d], bfr, acc1, 0, 0, 0);
        }
        int mcol = mstart + mloc + lc;
        // conv zero-pad corrections (rare lanes; swizzle term is 0 for mr=1 and mr=256)
        if (tb == 0 && mloc == 0 && lc == 0) {          // t2 = 0
            #pragma unroll
            for (int rr = 0; rr < 4; ++rr) {
                int co = lg * 4 + rr; float sum = 0.f;
                for (int j = 0; j < 32; ++j) {
                    int byte = (1 << 6) + (j >> 3) * 16 + (j & 7) * 2;
                    sum += wc0[(eo * 16 + co) * 32 + j] *
                           bf2f(*(const unsigned short*)((char*)lds + byte));
                }
                acc0[rr] -= sum;
            }
        }
        if (tb == (TIN / 256 - 1) && mloc == 240 && lc == 15) {   // t2 = 8191
            #pragma unroll
            for (int rr = 0; rr < 4; ++rr) {
                int co = lg * 4 + rr; float sum = 0.f;
                for (int j = 0; j < 32; ++j) {
                    int byte = (256 << 6) + (j >> 3) * 16 + (j & 7) * 2;
                    sum += wc2[(eo * 16 + co) * 32 + j] *
                           bf2f(*(const unsigned short*)((char*)lds + byte));
                }
                acc1[rr] -= sum;
            }
        }
        // epilogue: bias + LeakyReLU + packed even/odd store (dense float2)
        #pragma unroll
        for (int rr = 0; rr < 4; ++rr) {
            int co = lg * 4 + rr;
            float e = acc0[rr] + bco[rr];
            float o = acc1[rr] + bco[rr];
            e = (e >= 0.f) ? e : 0.2f * e;
            o = (o >= 0.f) ? o : 0.2f * o;
            float2 pr = make_float2(e, o);
            *(float2*)(obase + (size_t)co * T2V + 2 * mcol) = pr;
        }
    }
}

extern "C" void kernel_launch(void* const* d_in, const int* in_sizes, int n_in,
                              void* d_out, int out_size, void* d_ws, size_t ws_size,
                              hipStream_t stream) {
    const float* x    = (const float*)d_in[0];
    const float* w    = (const float*)d_in[1];
    const float* bias = (const float*)d_in[2];
    float* out = (float*)d_out;

    // workspace layout: abf 172032 B | wc0 57344 B | wc2 57344 B  (286720 B total)
    unsigned short* abf = (unsigned short*)d_ws;
    float* wc0 = (float*)((char*)d_ws + 172032);
    float* wc2 = (float*)((char*)d_ws + 172032 + 57344);

    prep_fold<<<42, 256, 0, stream>>>(w, abf, wc0, wc2);
    dim3 grid(TIN / 256, EDGES, NB);
    skel_main<<<grid, 256, 0, stream>>>(x, bias, abf, wc0, wc2, out);
}